// Round 1
// baseline (1471.005 us; speedup 1.0000x reference)
//
#include <hip/hip_runtime.h>
#include <stdint.h>

// Problem constants (fixed by setup_inputs)
#define NQ 256      // queries (B)
#define DD 768      // feature dim
#define NN 131072   // database rows
#define LL 512      // y dim
#define KC 32       // K-chunk staged in LDS
#define NT 64       // db rows per block tile

// Map float -> orderable uint (monotonic, handles negatives)
__device__ __forceinline__ unsigned int order_f32(float f) {
    unsigned int b = __float_as_uint(f);
    return (b & 0x80000000u) ? ~b : (b | 0x80000000u);
}

__global__ __launch_bounds__(256) void init_cand_kernel(unsigned long long* cand) {
    cand[threadIdx.x] = 0ull;   // 0 loses to every real candidate
}

// Fused: sim = dot(x_b, dx_n) / max(||dx_n||, eps); per-query argmax over this
// block's 64 rows; merge via one atomicMax per query.
// (Query-norm division is a per-query positive constant -> argmax-invariant.)
__global__ __launch_bounds__(256) void sim_argmax_kernel(
        const float* __restrict__ x,
        const float* __restrict__ dx,
        unsigned long long* __restrict__ cand) {
    // [kk][row] so inner-loop dx reads broadcast across tx; +1 pad for write banks
    __shared__ __align__(16) float dxs[KC][NT + 1];
    // [kk][q] transposed so inner-loop query reads are ds_read_b128, conflict-free
    __shared__ __align__(16) float xs[KC][NQ];
    __shared__ unsigned long long red[4 * 256];

    const int tid = (int)threadIdx.x;
    const int tx = tid & 15;        // query group
    const int ty = tid >> 4;        // row group
    const int base = (int)blockIdx.x * NT;

    float acc[4][16];               // [row i][query slot s], s = g*4+j, q = g*64 + tx*4 + j
    #pragma unroll
    for (int i = 0; i < 4; ++i)
        #pragma unroll
        for (int j = 0; j < 16; ++j)
            acc[i][j] = 0.f;
    float nrm2[4] = {0.f, 0.f, 0.f, 0.f};

    for (int k0 = 0; k0 < DD; k0 += KC) {
        // ---- stage db tile (64 rows x 32 k): 8 lanes cover 128B contiguous per row
        #pragma unroll
        for (int it = 0; it < (NT * KC / 4) / 256; ++it) {
            int l = tid + it * 256;
            int row = l >> 3;       // 0..63
            int c4 = l & 7;         // 0..7
            const float4 v = *(const float4*)(dx + (size_t)(base + row) * DD + (k0 + c4 * 4));
            dxs[c4 * 4 + 0][row] = v.x;
            dxs[c4 * 4 + 1][row] = v.y;
            dxs[c4 * 4 + 2][row] = v.z;
            dxs[c4 * 4 + 3][row] = v.w;
        }
        // ---- stage query tile (256 q x 32 k): q = tid (one 128B line per q, L2-hot)
        {
            const float* xrow = x + (size_t)tid * DD + k0;
            #pragma unroll
            for (int c4 = 0; c4 < 8; ++c4) {
                const float4 v = *(const float4*)(xrow + c4 * 4);
                xs[c4 * 4 + 0][tid] = v.x;   // bank = tid%32 -> 2-way (free)
                xs[c4 * 4 + 1][tid] = v.y;
                xs[c4 * 4 + 2][tid] = v.z;
                xs[c4 * 4 + 3][tid] = v.w;
            }
        }
        __syncthreads();
        #pragma unroll
        for (int kk = 0; kk < KC; ++kk) {
            const float d0 = dxs[kk][ty * 4 + 0];   // 16-lane broadcast, free
            const float d1 = dxs[kk][ty * 4 + 1];
            const float d2 = dxs[kk][ty * 4 + 2];
            const float d3 = dxs[kk][ty * 4 + 3];
            nrm2[0] += d0 * d0;
            nrm2[1] += d1 * d1;
            nrm2[2] += d2 * d2;
            nrm2[3] += d3 * d3;
            #pragma unroll
            for (int g = 0; g < 4; ++g) {
                const float4 xv = *(const float4*)&xs[kk][g * 64 + tx * 4]; // b128, free
                acc[0][g*4+0] += d0 * xv.x; acc[0][g*4+1] += d0 * xv.y;
                acc[0][g*4+2] += d0 * xv.z; acc[0][g*4+3] += d0 * xv.w;
                acc[1][g*4+0] += d1 * xv.x; acc[1][g*4+1] += d1 * xv.y;
                acc[1][g*4+2] += d1 * xv.z; acc[1][g*4+3] += d1 * xv.w;
                acc[2][g*4+0] += d2 * xv.x; acc[2][g*4+1] += d2 * xv.y;
                acc[2][g*4+2] += d2 * xv.z; acc[2][g*4+3] += d2 * xv.w;
                acc[3][g*4+0] += d3 * xv.x; acc[3][g*4+1] += d3 * xv.y;
                acc[3][g*4+2] += d3 * xv.z; acc[3][g*4+3] += d3 * xv.w;
            }
        }
        __syncthreads();
    }

    float rinv[4];
    #pragma unroll
    for (int i = 0; i < 4; ++i)
        rinv[i] = 1.0f / fmaxf(sqrtf(nrm2[i]), 1e-8f);

    // best over this thread's 4 rows, per query slot.
    // pack = (orderable_score << 32) | ~row  -> ties prefer smaller row (numpy argmax)
    unsigned long long best[16];
    #pragma unroll
    for (int s = 0; s < 16; ++s) {
        unsigned long long c = 0ull;
        #pragma unroll
        for (int i = 0; i < 4; ++i) {
            const float sc = acc[i][s] * rinv[i];
            const unsigned int row = (unsigned int)(base + ty * 4 + i);
            const unsigned long long p =
                ((unsigned long long)order_f32(sc) << 32) | (unsigned long long)(unsigned int)(~row);
            c = (p > c) ? p : c;
        }
        best[s] = c;
    }
    // reduce over the wave's 4 ty values (tid ^16, ^32 stay in-wave)
    #pragma unroll
    for (int s = 0; s < 16; ++s) {
        unsigned long long c = best[s];
        unsigned long long o = __shfl_xor(c, 16, 64);
        c = (o > c) ? o : c;
        o = __shfl_xor(c, 32, 64);
        c = (o > c) ? o : c;
        best[s] = c;
    }
    const int wave = tid >> 6;
    const int lane = tid & 63;
    if (lane < 16) {
        #pragma unroll
        for (int s = 0; s < 16; ++s)
            red[wave * 256 + s * 16 + lane] = best[s];
    }
    __syncthreads();
    {
        unsigned long long c = red[tid];
        unsigned long long o = red[256 + tid]; c = (o > c) ? o : c;
        o = red[512 + tid]; c = (o > c) ? o : c;
        o = red[768 + tid]; c = (o > c) ? o : c;
        const int s = tid >> 4;
        const int txx = tid & 15;
        const int q = (s >> 2) * 64 + txx * 4 + (s & 3);
        atomicMax(&cand[q], c);
    }
}

__global__ __launch_bounds__(128) void gather_kernel(
        const unsigned long long* __restrict__ cand,
        const float* __restrict__ dy,
        float* __restrict__ out) {
    const int q = (int)blockIdx.x;
    const unsigned int row = ~(unsigned int)(cand[q] & 0xFFFFFFFFull);
    const float4* src = (const float4*)(dy + (size_t)row * LL);
    float4* dst = (float4*)(out + (size_t)q * LL);
    dst[threadIdx.x] = src[threadIdx.x];    // LL/4 = 128 float4s
}

extern "C" void kernel_launch(void* const* d_in, const int* in_sizes, int n_in,
                              void* d_out, int out_size, void* d_ws, size_t ws_size,
                              hipStream_t stream) {
    const float* x  = (const float*)d_in[0];   // imu, 256*6*128 = 256x768
    const float* dx = (const float*)d_in[1];   // database_x, 131072x768
    const float* dy = (const float*)d_in[2];   // database_y, 131072x512
    float* out = (float*)d_out;                // 256x512
    unsigned long long* cand = (unsigned long long*)d_ws;  // 256 * 8B

    init_cand_kernel<<<1, 256, 0, stream>>>(cand);
    sim_argmax_kernel<<<NN / NT, 256, 0, stream>>>(x, dx, cand);
    gather_kernel<<<NQ, 128, 0, stream>>>(cand, dy, out);
}

// Round 2
// 674.116 us; speedup vs baseline: 2.1821x; 2.1821x over previous
//
#include <hip/hip_runtime.h>
#include <stdint.h>

// Problem constants (fixed by setup_inputs)
#define NQ 256      // queries (B)
#define DD 768      // feature dim
#define NN 131072   // database rows
#define LL 512      // y dim
#define KC2 32      // K per staged B chunk
#define NCHUNK (DD / KC2)   // 24
#define RPB 128     // db rows per block (4 waves x 32)
#define RPW 32      // db rows per wave

typedef __bf16 bf16x8 __attribute__((ext_vector_type(8)));
typedef float f32x16 __attribute__((ext_vector_type(16)));

union FragU {
    unsigned short u[8];
    bf16x8 v;
    uint4 q;
};

__device__ __forceinline__ unsigned short f32_bf16_rne(float f) {
    unsigned int u = __float_as_uint(f);
    u += 0x7FFFu + ((u >> 16) & 1u);
    return (unsigned short)(u >> 16);
}

// Map float -> orderable uint (monotonic, handles negatives)
__device__ __forceinline__ unsigned int order_f32(float f) {
    unsigned int b = __float_as_uint(f);
    return (b & 0x80000000u) ? ~b : (b | 0x80000000u);
}

__global__ __launch_bounds__(256) void init_cand_kernel(unsigned long long* cand) {
    cand[threadIdx.x] = 0ull;   // 0 loses to every real candidate
}

// Convert queries x[256][768] fp32 -> B-fragments (hi/lo bf16) in MFMA layout.
// Layout (ushort8 units): [c(24)][s(2)][t(8)][v(2)][lane(64)] -> unit index
//   = c*2048 + s*1024 + t*128 + v*64 + lane, each unit = 8 bf16 along k.
// Element: n = t*32 + (lane&31); k = c*32 + s*16 + (lane>>5)*8 + j.
__global__ __launch_bounds__(256) void bfrag_prep_kernel(
        const float* __restrict__ x, unsigned short* __restrict__ bfrag) {
    const int gid = (int)blockIdx.x * 256 + (int)threadIdx.x;   // 0..49151
    const int lane = gid & 63;
    const int v = (gid >> 6) & 1;
    const int t = (gid >> 7) & 7;
    const int s = (gid >> 10) & 1;
    const int c = gid >> 11;                 // 0..23
    const int n = t * 32 + (lane & 31);
    const int kb = c * KC2 + s * 16 + (lane >> 5) * 8;
    const float* xp = x + (size_t)n * DD + kb;
    const float4 v0 = *(const float4*)xp;
    const float4 v1 = *(const float4*)(xp + 4);
    const float f[8] = {v0.x, v0.y, v0.z, v0.w, v1.x, v1.y, v1.z, v1.w};
    FragU fr;
    #pragma unroll
    for (int j = 0; j < 8; ++j) {
        const unsigned short h = f32_bf16_rne(f[j]);
        if (v == 0) {
            fr.u[j] = h;
        } else {
            const float hf = __uint_as_float((unsigned int)h << 16);
            fr.u[j] = f32_bf16_rne(f[j] - hf);
        }
    }
    *(uint4*)(bfrag + (size_t)gid * 8) = fr.q;
}

// Split-bf16 MFMA: score[row][q] = (Ah+Al)·(Bh+Bl) ~ AhBh + AlBh + AhBl,
// row-norms accumulated in fp32 during conversion; fused per-query argmax.
__global__ __launch_bounds__(256, 2) void sim_mfma_kernel(
        const float* __restrict__ dx,
        const unsigned short* __restrict__ bfrag,
        unsigned long long* __restrict__ cand) {
    __shared__ unsigned short ldsB[KC2 * NQ * 2];     // 32 KB, one B chunk
    __shared__ unsigned long long red[4 * NQ];        // 8 KB epilogue

    const int tid = (int)threadIdx.x;
    const int lane = tid & 63;
    const int w = tid >> 6;
    const int lhalf = lane >> 5;
    const int lrow = lane & 31;
    const int baserow = (int)blockIdx.x * RPB + w * RPW;
    const int myrow = baserow + lrow;
    const float* arow = dx + (size_t)myrow * DD + lhalf * 8;

    f32x16 acc[8];
    #pragma unroll
    for (int t = 0; t < 8; ++t)
        #pragma unroll
        for (int r = 0; r < 16; ++r)
            acc[t][r] = 0.f;

    float nrm2 = 0.f;

    float4 a_cur[2][2], a_nxt[2][2];
    #pragma unroll
    for (int s = 0; s < 2; ++s) {       // prefetch chunk 0
        a_nxt[s][0] = *(const float4*)(arow + s * 16);
        a_nxt[s][1] = *(const float4*)(arow + s * 16 + 4);
    }

    #pragma unroll 1
    for (int c = 0; c < NCHUNK; ++c) {
        __syncthreads();    // all waves done reading previous chunk's ldsB
        {
            // DMA B chunk c: 32 KB, frag-ordered; wave-uniform LDS base + lane*16B
            const unsigned short* gB = bfrag + (size_t)c * (KC2 * NQ * 2);
            #pragma unroll
            for (int i = 0; i < 8; ++i) {
                const int blk = w * 8 + i;                       // 1 KB blocks
                const unsigned short* gp = gB + blk * 512 + lane * 8;
                unsigned short* lp = &ldsB[blk * 512];
                __builtin_amdgcn_global_load_lds(
                    (const __attribute__((address_space(1))) unsigned int*)(const void*)gp,
                    (__attribute__((address_space(3))) unsigned int*)(void*)lp,
                    16, 0, 0);
            }
        }
        __syncthreads();    // vmcnt(0) drain -> DMA complete

        // rotate A regs; issue next chunk's A loads (2 ksteps of compute to hide)
        #pragma unroll
        for (int s = 0; s < 2; ++s) {
            a_cur[s][0] = a_nxt[s][0];
            a_cur[s][1] = a_nxt[s][1];
        }
        {
            const int cn = (c + 1 < NCHUNK) ? (c + 1) : 0;   // clamp: no OOB tail read
            const float* ap = arow + cn * KC2;
            #pragma unroll
            for (int s = 0; s < 2; ++s) {
                a_nxt[s][0] = *(const float4*)(ap + s * 16);
                a_nxt[s][1] = *(const float4*)(ap + s * 16 + 4);
            }
        }

        #pragma unroll
        for (int s = 0; s < 2; ++s) {
            // in-register fp32 -> bf16 hi/lo conversion + norm accumulation
            FragU ah, al;
            const float f[8] = {a_cur[s][0].x, a_cur[s][0].y, a_cur[s][0].z, a_cur[s][0].w,
                                a_cur[s][1].x, a_cur[s][1].y, a_cur[s][1].z, a_cur[s][1].w};
            #pragma unroll
            for (int j = 0; j < 8; ++j) {
                const float vv = f[j];
                nrm2 += vv * vv;
                const unsigned short h = f32_bf16_rne(vv);
                ah.u[j] = h;
                al.u[j] = f32_bf16_rne(vv - __uint_as_float((unsigned int)h << 16));
            }
            #pragma unroll
            for (int t = 0; t < 8; ++t) {
                const bf16x8 bh = *(const bf16x8*)&ldsB[(s * 1024 + t * 128 + lane) * 8];
                const bf16x8 bl = *(const bf16x8*)&ldsB[(s * 1024 + t * 128 + 64 + lane) * 8];
                acc[t] = __builtin_amdgcn_mfma_f32_32x32x16_bf16(ah.v, bh, acc[t], 0, 0, 0);
                acc[t] = __builtin_amdgcn_mfma_f32_32x32x16_bf16(al.v, bh, acc[t], 0, 0, 0);
                acc[t] = __builtin_amdgcn_mfma_f32_32x32x16_bf16(ah.v, bl, acc[t], 0, 0, 0);
            }
        }
    }

    // ---- epilogue: norms, scores, fused argmax ----
    nrm2 += __shfl_xor(nrm2, 32, 64);            // lanes l, l^32 cover complementary k
    const float rinv = 1.0f / fmaxf(sqrtf(nrm2), 1e-8f);

    float rv[16];                                 // rinv for each C/D reg's row
    #pragma unroll
    for (int r = 0; r < 16; ++r) {
        const int rl = (r & 3) + 8 * (r >> 2) + 4 * lhalf;  // verified 32x32 C/D map
        rv[r] = __shfl(rinv, rl, 64);             // lane rl holds row baserow+rl
    }

    #pragma unroll
    for (int t = 0; t < 8; ++t) {
        unsigned long long best = 0ull;
        #pragma unroll
        for (int r = 0; r < 16; ++r) {
            const int rl = (r & 3) + 8 * (r >> 2) + 4 * lhalf;
            const float sc = acc[t][r] * rv[r];
            const unsigned long long p =
                ((unsigned long long)order_f32(sc) << 32) |
                (unsigned long long)(unsigned int)(~(unsigned int)(baserow + rl));
            best = (p > best) ? p : best;        // ties -> smaller row (numpy argmax)
        }
        const unsigned long long o = __shfl_xor(best, 32, 64);  // other row-half, same col
        best = (o > best) ? o : best;
        if (lane < 32)
            red[w * NQ + t * 32 + lrow] = best;  // col = t*32 + (lane&31)
    }
    __syncthreads();
    if (tid < NQ) {
        unsigned long long m0 = red[tid];
        unsigned long long m1 = red[NQ + tid];
        unsigned long long m2 = red[2 * NQ + tid];
        unsigned long long m3 = red[3 * NQ + tid];
        m0 = (m1 > m0) ? m1 : m0;
        m2 = (m3 > m2) ? m3 : m2;
        m0 = (m2 > m0) ? m2 : m0;
        atomicMax(&cand[tid], m0);
    }
}

__global__ __launch_bounds__(128) void gather_kernel(
        const unsigned long long* __restrict__ cand,
        const float* __restrict__ dy,
        float* __restrict__ out) {
    const int q = (int)blockIdx.x;
    const unsigned int row = ~(unsigned int)(cand[q] & 0xFFFFFFFFull);
    const float4* src = (const float4*)(dy + (size_t)row * LL);
    float4* dst = (float4*)(out + (size_t)q * LL);
    dst[threadIdx.x] = src[threadIdx.x];    // LL/4 = 128 float4s
}

extern "C" void kernel_launch(void* const* d_in, const int* in_sizes, int n_in,
                              void* d_out, int out_size, void* d_ws, size_t ws_size,
                              hipStream_t stream) {
    const float* x  = (const float*)d_in[0];   // imu, 256x768
    const float* dx = (const float*)d_in[1];   // database_x, 131072x768
    const float* dy = (const float*)d_in[2];   // database_y, 131072x512
    float* out = (float*)d_out;                // 256x512

    unsigned long long* cand = (unsigned long long*)d_ws;              // 2 KB
    unsigned short* bfrag = (unsigned short*)((char*)d_ws + 4096);     // 786 KB

    init_cand_kernel<<<1, 256, 0, stream>>>(cand);
    bfrag_prep_kernel<<<192, 256, 0, stream>>>(x, bfrag);
    sim_mfma_kernel<<<NN / RPB, 256, 0, stream>>>(dx, bfrag, cand);
    gather_kernel<<<NQ, 128, 0, stream>>>(cand, dy, out);
}